// Round 11
// baseline (595.138 us; speedup 1.0000x reference)
//
#include <hip/hip_runtime.h>
#include <hip/hip_bf16.h>
#include <hip/hip_fp16.h>

#define NROWS 16384   // B*T
#define FEATD 256
#define F1D   512
#define SZD   192     // action_dim * atoms

typedef unsigned short u16;
typedef float    f32x4  __attribute__((ext_vector_type(4)));
typedef short    bf16x8 __attribute__((ext_vector_type(8)));
typedef _Float16 f16x8  __attribute__((ext_vector_type(8)));
typedef unsigned short u16x8 __attribute__((ext_vector_type(8)));

#define LO_SCALE 2048.0f
#define LO_INV   (1.0f / 2048.0f)

__device__ __forceinline__ float sigmoid_f(float x) { return 1.0f / (1.0f + expf(-x)); }

__device__ __forceinline__ float gelu_f(float x) {
    float x3 = x * x * x;
    float inner = 0.7978845608028654f * (x + 0.044715f * x3);
    return 0.5f * x * (1.0f + tanhf(inner));
}

__device__ __forceinline__ u16 f2bf(float f) {
    unsigned u = __float_as_uint(f);
    u = (u + 0x7FFFu + ((u >> 16) & 1u)) >> 16;
    return (u16)u;
}
__device__ __forceinline__ float bf2f(u16 h) { return __uint_as_float(((unsigned)h) << 16); }

__device__ __forceinline__ u16 f2h_u(float f)  { return __half_as_ushort(__float2half(f)); }
__device__ __forceinline__ float h2f_u(u16 u)  { return __half2float(__ushort_as_half(u)); }

// f16 scaled-split: hi = f16(x); lo' = f16(2048*(x-hi)) — always normal
__device__ __forceinline__ void split8hs(float4 a, float4 b, u16x8& hi, u16x8& lo) {
    float v[8] = {a.x, a.y, a.z, a.w, b.x, b.y, b.z, b.w};
    #pragma unroll
    for (int i = 0; i < 8; ++i) {
        u16 h = f2h_u(v[i]);
        hi[i] = h;
        lo[i] = f2h_u((v[i] - h2f_u(h)) * LO_SCALE);
    }
}

// LDS offset (halves), 64B rows, XOR slot swizzle -> frag reads 2-way max
__device__ __forceinline__ int lofs(int row, int chunk) {
    return row * 32 + ((chunk ^ ((row >> 1) & 3)) << 3);
}

// XCD-contiguous block swizzle (nwg % 8 == 0 in all grids here)
template<int TM, int TN, int NCT>
__device__ __forceinline__ void xcd_tile(int& row0, int& col0) {
    int b   = blockIdx.x + gridDim.x * blockIdx.y;
    int nwg = gridDim.x * gridDim.y;
    int q   = nwg >> 3;
    int swz = (b & 7) * q + (b >> 3);
    col0 = (swz % NCT) * TN;
    row0 = (swz / NCT) * TM;
}

// ---------------------------------------------------------------------------
// weight prep (f16 scaled-split, transposed [N][K]); optional tanh*sig fuse
// ---------------------------------------------------------------------------
__global__ void wprep_f16_kernel(const float* __restrict__ src, const float* __restrict__ src2,
                                 u16* __restrict__ dhi, u16* __restrict__ dlo, int Kd, int Nd)
{
    int idx = blockIdx.x * blockDim.x + threadIdx.x;
    if (idx >= Kd * Nd) return;
    int n = idx / Kd, k = idx - n * Kd;
    float v = src[(size_t)k * Nd + n];
    if (src2) v = tanhf(v) * sigmoid_f(src2[(size_t)k * Nd + n]);
    u16 h = f2h_u(v);
    dhi[idx] = h;
    dlo[idx] = f2h_u((v - h2f_u(h)) * LO_SCALE);
}

// weight prep (bf16 split, transposed): fc1e/fc2e weights
__global__ void wprep2_kernel(const float* __restrict__ src,
                              u16* __restrict__ dhi, u16* __restrict__ dlo, int Kd, int Nd)
{
    int idx = blockIdx.x * blockDim.x + threadIdx.x;
    if (idx >= Kd * Nd) return;
    int n = idx / Kd, k = idx - n * Kd;
    float v = src[(size_t)k * Nd + n];
    u16 h = f2bf(v);
    dhi[idx] = h;
    dlo[idx] = f2bf(v - bf2f(h));
}

// band compaction: Kb[4][512] (kron(I,kn)*we), W3b[15][512] ((W3*we) band)
__global__ __launch_bounds__(512)
void prep2_kernel(const float* __restrict__ kn, const float* __restrict__ we,
                  const float* __restrict__ W3,
                  float* __restrict__ Kb, float* __restrict__ W3b, int m)
{
    int j = threadIdx.x;
    if (j >= F1D) return;
    int jb = (j / m) * m;
    int jm = j - jb;
    for (int t = 0; t < 4; ++t) {
        int i = jb + t;
        float v = 0.0f;
        if (t < m && i < F1D)
            v = kn[t * m + jm] * we[(size_t)i * F1D + j];
        Kb[t * F1D + j] = v;
    }
    for (int d = 0; d < 15; ++d) {
        int i = j - 7 + d;
        float v = 0.0f;
        if (i >= 0 && i < F1D)
            v = W3[(size_t)i * F1D + j] * we[(size_t)i * F1D + j];
        W3b[d * F1D + j] = v;
    }
}

// per-column nonzero row start of w + compact band wb[4][192]
__global__ void colrange_wband_kernel(const float* __restrict__ w, int* __restrict__ cs,
                                      float* __restrict__ wb)
{
    int c = blockIdx.x * blockDim.x + threadIdx.x;
    if (c >= SZD) return;
    int s = 0, e = -1;
    for (int r = 0; r < F1D; ++r) {
        if (w[(size_t)r * SZD + c] != 0.0f) { if (e < 0) s = r; e = r; }
    }
    cs[c] = s;
    for (int t = 0; t < 4; ++t)
        wb[t * SZD + c] = (s + t <= e) ? w[(size_t)(s + t) * SZD + c] : 0.0f;
}

// ---------------------------------------------------------------------------
// NALU layer 1: block 128x64, 4 waves of 64x32 (fr=4, fc=2).
// f32 features in (log+split fused); f16-pair outputs.
// ---------------------------------------------------------------------------
template<int K>
__global__ __launch_bounds__(256, 1)
void nalu_l1_kernel(const float* __restrict__ x1,
                    const u16* __restrict__ Wh, const u16* __restrict__ Wl,
                    const u16* __restrict__ Gh, const u16* __restrict__ Gl,
                    u16* __restrict__ o1h, u16* __restrict__ o1l,
                    u16* __restrict__ o2h, u16* __restrict__ o2l)
{
    __shared__ u16 A1h[128 * 32], A1l[128 * 32];
    __shared__ u16 A2h[128 * 32], A2l[128 * 32];
    __shared__ u16 BWh[64 * 32],  BWl[64 * 32];
    __shared__ u16 BGh[64 * 32],  BGl[64 * 32];

    const int t = threadIdx.x;
    const int lane = t & 63;
    const int wv = t >> 6;
    const int wr = wv >> 1, wc = wv & 1;
    const int lr = lane & 15, lk = lane >> 4;
    int row0, col0;
    xcd_tile<128, 64, 8>(row0, col0);
    const int sr = t >> 2;
    const int kc = t & 3;

    // hoisted LDS offsets (loop-invariant)
    int aofs[4], bofs[2];
    #pragma unroll
    for (int fr = 0; fr < 4; ++fr) aofs[fr] = lofs(wr * 64 + fr * 16 + lr, lk);
    #pragma unroll
    for (int fc = 0; fc < 2; ++fc) bofs[fc] = lofs(wc * 32 + fc * 16 + lr, lk);
    const int so0 = lofs(sr, kc);
    const int so1 = lofs(64 + sr, kc);

    f32x4 aA[4][2], aAx[4][2], aM[4][2], aMx[4][2], aG[4][2], aGx[4][2];
    #pragma unroll
    for (int i = 0; i < 4; ++i)
        #pragma unroll
        for (int j = 0; j < 2; ++j) {
            aA[i][j] = 0; aAx[i][j] = 0;
            aM[i][j] = 0; aMx[i][j] = 0;
            aG[i][j] = 0; aGx[i][j] = 0;
        }

    for (int k0 = 0; k0 < K; k0 += 32) {
        u16x8 v1h[2], v1l[2], v2h[2], v2l[2];
        #pragma unroll
        for (int p = 0; p < 2; ++p) {
            const float* px1 = x1 + (size_t)(row0 + p * 64 + sr) * K + k0 + kc * 8;
            float4 f0 = *(const float4*)px1;
            float4 f1 = *(const float4*)(px1 + 4);
            split8hs(f0, f1, v1h[p], v1l[p]);
            float4 e0, e1;
            e0.x = logf(fabsf(f0.x) + 1e-7f); e0.y = logf(fabsf(f0.y) + 1e-7f);
            e0.z = logf(fabsf(f0.z) + 1e-7f); e0.w = logf(fabsf(f0.w) + 1e-7f);
            e1.x = logf(fabsf(f1.x) + 1e-7f); e1.y = logf(fabsf(f1.y) + 1e-7f);
            e1.z = logf(fabsf(f1.z) + 1e-7f); e1.w = logf(fabsf(f1.w) + 1e-7f);
            split8hs(e0, e1, v2h[p], v2l[p]);
        }
        const size_t brow = (size_t)(col0 + sr) * K + k0 + kc * 8;
        u16x8 vwh = *(const u16x8*)(Wh + brow);
        u16x8 vwl = *(const u16x8*)(Wl + brow);
        u16x8 vgh = *(const u16x8*)(Gh + brow);
        u16x8 vgl = *(const u16x8*)(Gl + brow);

        __syncthreads();
        *(u16x8*)&A1h[so0] = v1h[0];  *(u16x8*)&A1h[so1] = v1h[1];
        *(u16x8*)&A1l[so0] = v1l[0];  *(u16x8*)&A1l[so1] = v1l[1];
        *(u16x8*)&A2h[so0] = v2h[0];  *(u16x8*)&A2h[so1] = v2h[1];
        *(u16x8*)&A2l[so0] = v2l[0];  *(u16x8*)&A2l[so1] = v2l[1];
        *(u16x8*)&BWh[so0] = vwh;     *(u16x8*)&BWl[so0] = vwl;
        *(u16x8*)&BGh[so0] = vgh;     *(u16x8*)&BGl[so0] = vgl;
        __syncthreads();

        f16x8 bwh[2], bwl[2], bgh[2], bgl[2];
        #pragma unroll
        for (int fc = 0; fc < 2; ++fc) {
            bwh[fc] = *(f16x8*)&BWh[bofs[fc]];
            bwl[fc] = *(f16x8*)&BWl[bofs[fc]];
            bgh[fc] = *(f16x8*)&BGh[bofs[fc]];
            bgl[fc] = *(f16x8*)&BGl[bofs[fc]];
        }
        #pragma unroll
        for (int fr = 0; fr < 4; ++fr) {
            f16x8 a1h = *(f16x8*)&A1h[aofs[fr]];
            f16x8 a1l = *(f16x8*)&A1l[aofs[fr]];
            f16x8 a2h = *(f16x8*)&A2h[aofs[fr]];
            f16x8 a2l = *(f16x8*)&A2l[aofs[fr]];
            #pragma unroll
            for (int fc = 0; fc < 2; ++fc) {
                aA [fr][fc] = __builtin_amdgcn_mfma_f32_16x16x32_f16(a1h, bwh[fc], aA [fr][fc], 0, 0, 0);
                aAx[fr][fc] = __builtin_amdgcn_mfma_f32_16x16x32_f16(a1h, bwl[fc], aAx[fr][fc], 0, 0, 0);
                aAx[fr][fc] = __builtin_amdgcn_mfma_f32_16x16x32_f16(a1l, bwh[fc], aAx[fr][fc], 0, 0, 0);
                aM [fr][fc] = __builtin_amdgcn_mfma_f32_16x16x32_f16(a2h, bwh[fc], aM [fr][fc], 0, 0, 0);
                aMx[fr][fc] = __builtin_amdgcn_mfma_f32_16x16x32_f16(a2h, bwl[fc], aMx[fr][fc], 0, 0, 0);
                aMx[fr][fc] = __builtin_amdgcn_mfma_f32_16x16x32_f16(a2l, bwh[fc], aMx[fr][fc], 0, 0, 0);
                aG [fr][fc] = __builtin_amdgcn_mfma_f32_16x16x32_f16(a1h, bgh[fc], aG [fr][fc], 0, 0, 0);
                aGx[fr][fc] = __builtin_amdgcn_mfma_f32_16x16x32_f16(a1h, bgl[fc], aGx[fr][fc], 0, 0, 0);
                aGx[fr][fc] = __builtin_amdgcn_mfma_f32_16x16x32_f16(a1l, bgh[fc], aGx[fr][fc], 0, 0, 0);
            }
        }
    }

    #pragma unroll
    for (int fr = 0; fr < 4; ++fr)
        #pragma unroll
        for (int fc = 0; fc < 2; ++fc) {
            int colg = col0 + wc * 32 + fc * 16 + lr;
            int rowb = row0 + wr * 64 + fr * 16 + lk * 4;
            #pragma unroll
            for (int i = 0; i < 4; ++i) {
                float a  = aA[fr][fc][i] + aAx[fr][fc][i] * LO_INV;
                float mm = aM[fr][fc][i] + aMx[fr][fc][i] * LO_INV;
                float g  = aG[fr][fc][i] + aGx[fr][fc][i] * LO_INV;
                float m_ = expf(fminf(fmaxf(mm, -20.0f), 20.0f));
                float gs = sigmoid_f(g);
                float h11v = gelu_f(a);
                float h12v = gelu_f(gs * a + (1.0f - gs) * m_);
                float lgv  = logf(fabsf(h12v) + 1e-7f);
                size_t oi = (size_t)(rowb + i) * F1D + colg;
                u16 hh = f2h_u(h11v);
                o1h[oi] = hh;
                o1l[oi] = f2h_u((h11v - h2f_u(hh)) * LO_SCALE);
                u16 lh = f2h_u(lgv);
                o2h[oi] = lh;
                o2l[oi] = f2h_u((lgv - h2f_u(lh)) * LO_SCALE);
            }
        }
}

// ---------------------------------------------------------------------------
// NALU layer 2: same 128x64 / 64x32-wave tiling; f16-pair in, bf16-pair h out
// ---------------------------------------------------------------------------
template<int K>
__global__ __launch_bounds__(256, 1)
void nalu_l2_kernel(const u16* __restrict__ x1h, const u16* __restrict__ x1l,
                    const u16* __restrict__ x2h, const u16* __restrict__ x2l,
                    const u16* __restrict__ Wh, const u16* __restrict__ Wl,
                    const u16* __restrict__ Gh, const u16* __restrict__ Gl,
                    u16* __restrict__ ohh, u16* __restrict__ ohl)
{
    __shared__ u16 A1h[128 * 32], A1l[128 * 32];
    __shared__ u16 A2h[128 * 32], A2l[128 * 32];
    __shared__ u16 BWh[64 * 32],  BWl[64 * 32];
    __shared__ u16 BGh[64 * 32],  BGl[64 * 32];

    const int t = threadIdx.x;
    const int lane = t & 63;
    const int wv = t >> 6;
    const int wr = wv >> 1, wc = wv & 1;
    const int lr = lane & 15, lk = lane >> 4;
    int row0, col0;
    xcd_tile<128, 64, 8>(row0, col0);
    const int sr = t >> 2;
    const int kc = t & 3;

    int aofs[4], bofs[2];
    #pragma unroll
    for (int fr = 0; fr < 4; ++fr) aofs[fr] = lofs(wr * 64 + fr * 16 + lr, lk);
    #pragma unroll
    for (int fc = 0; fc < 2; ++fc) bofs[fc] = lofs(wc * 32 + fc * 16 + lr, lk);
    const int so0 = lofs(sr, kc);
    const int so1 = lofs(64 + sr, kc);

    f32x4 aA[4][2], aAx[4][2], aM[4][2], aMx[4][2], aG[4][2], aGx[4][2];
    #pragma unroll
    for (int i = 0; i < 4; ++i)
        #pragma unroll
        for (int j = 0; j < 2; ++j) {
            aA[i][j] = 0; aAx[i][j] = 0;
            aM[i][j] = 0; aMx[i][j] = 0;
            aG[i][j] = 0; aGx[i][j] = 0;
        }

    for (int k0 = 0; k0 < K; k0 += 32) {
        u16x8 v1h[2], v1l[2], v2h[2], v2l[2];
        #pragma unroll
        for (int p = 0; p < 2; ++p) {
            const size_t arow = (size_t)(row0 + p * 64 + sr) * K + k0 + kc * 8;
            v1h[p] = *(const u16x8*)(x1h + arow);
            v1l[p] = *(const u16x8*)(x1l + arow);
            v2h[p] = *(const u16x8*)(x2h + arow);
            v2l[p] = *(const u16x8*)(x2l + arow);
        }
        const size_t brow = (size_t)(col0 + sr) * K + k0 + kc * 8;
        u16x8 vwh = *(const u16x8*)(Wh + brow);
        u16x8 vwl = *(const u16x8*)(Wl + brow);
        u16x8 vgh = *(const u16x8*)(Gh + brow);
        u16x8 vgl = *(const u16x8*)(Gl + brow);

        __syncthreads();
        *(u16x8*)&A1h[so0] = v1h[0];  *(u16x8*)&A1h[so1] = v1h[1];
        *(u16x8*)&A1l[so0] = v1l[0];  *(u16x8*)&A1l[so1] = v1l[1];
        *(u16x8*)&A2h[so0] = v2h[0];  *(u16x8*)&A2h[so1] = v2h[1];
        *(u16x8*)&A2l[so0] = v2l[0];  *(u16x8*)&A2l[so1] = v2l[1];
        *(u16x8*)&BWh[so0] = vwh;     *(u16x8*)&BWl[so0] = vwl;
        *(u16x8*)&BGh[so0] = vgh;     *(u16x8*)&BGl[so0] = vgl;
        __syncthreads();

        f16x8 bwh[2], bwl[2], bgh[2], bgl[2];
        #pragma unroll
        for (int fc = 0; fc < 2; ++fc) {
            bwh[fc] = *(f16x8*)&BWh[bofs[fc]];
            bwl[fc] = *(f16x8*)&BWl[bofs[fc]];
            bgh[fc] = *(f16x8*)&BGh[bofs[fc]];
            bgl[fc] = *(f16x8*)&BGl[bofs[fc]];
        }
        #pragma unroll
        for (int fr = 0; fr < 4; ++fr) {
            f16x8 a1h = *(f16x8*)&A1h[aofs[fr]];
            f16x8 a1l = *(f16x8*)&A1l[aofs[fr]];
            f16x8 a2h = *(f16x8*)&A2h[aofs[fr]];
            f16x8 a2l = *(f16x8*)&A2l[aofs[fr]];
            #pragma unroll
            for (int fc = 0; fc < 2; ++fc) {
                aA [fr][fc] = __builtin_amdgcn_mfma_f32_16x16x32_f16(a1h, bwh[fc], aA [fr][fc], 0, 0, 0);
                aAx[fr][fc] = __builtin_amdgcn_mfma_f32_16x16x32_f16(a1h, bwl[fc], aAx[fr][fc], 0, 0, 0);
                aAx[fr][fc] = __builtin_amdgcn_mfma_f32_16x16x32_f16(a1l, bwh[fc], aAx[fr][fc], 0, 0, 0);
                aM [fr][fc] = __builtin_amdgcn_mfma_f32_16x16x32_f16(a2h, bwh[fc], aM [fr][fc], 0, 0, 0);
                aMx[fr][fc] = __builtin_amdgcn_mfma_f32_16x16x32_f16(a2h, bwl[fc], aMx[fr][fc], 0, 0, 0);
                aMx[fr][fc] = __builtin_amdgcn_mfma_f32_16x16x32_f16(a2l, bwh[fc], aMx[fr][fc], 0, 0, 0);
                aG [fr][fc] = __builtin_amdgcn_mfma_f32_16x16x32_f16(a1h, bgh[fc], aG [fr][fc], 0, 0, 0);
                aGx[fr][fc] = __builtin_amdgcn_mfma_f32_16x16x32_f16(a1h, bgl[fc], aGx[fr][fc], 0, 0, 0);
                aGx[fr][fc] = __builtin_amdgcn_mfma_f32_16x16x32_f16(a1l, bgh[fc], aGx[fr][fc], 0, 0, 0);
            }
        }
    }

    #pragma unroll
    for (int fr = 0; fr < 4; ++fr)
        #pragma unroll
        for (int fc = 0; fc < 2; ++fc) {
            int colg = col0 + wc * 32 + fc * 16 + lr;
            int rowb = row0 + wr * 64 + fr * 16 + lk * 4;
            #pragma unroll
            for (int i = 0; i < 4; ++i) {
                float a  = aA[fr][fc][i] + aAx[fr][fc][i] * LO_INV;
                float mm = aM[fr][fc][i] + aMx[fr][fc][i] * LO_INV;
                float g  = aG[fr][fc][i] + aGx[fr][fc][i] * LO_INV;
                float m_ = expf(fminf(fmaxf(mm, -20.0f), 20.0f));
                float gs = sigmoid_f(g);
                float hav = gelu_f(a);
                float htv = gelu_f(gs * a + (1.0f - gs) * m_);
                size_t base = (size_t)(rowb + i) * (2 * F1D) + colg;
                u16 ah = f2bf(hav);
                ohh[base] = ah;
                ohl[base] = f2bf(hav - bf2f(ah));
                u16 th = f2bf(htv);
                ohh[base + F1D] = th;
                ohl[base + F1D] = f2bf(htv - bf2f(th));
            }
        }
}

// ---------------------------------------------------------------------------
// GEMM + bias: block 128x128, 4 waves of 64x64 (fr=4, fc=4), bf16-pair ops
// ---------------------------------------------------------------------------
template<int K>
__global__ __launch_bounds__(256)
void gemm_mfma_kernel(const u16* __restrict__ Ahp, const u16* __restrict__ Alp,
                      const u16* __restrict__ Bh, const u16* __restrict__ Bl,
                      const float* __restrict__ bias, float* __restrict__ out)
{
    __shared__ u16 Ah[128 * 32], Al[128 * 32];
    __shared__ u16 Bsh[128 * 32], Bsl[128 * 32];

    const int t = threadIdx.x;
    const int lane = t & 63;
    const int wv = t >> 6;
    const int wr = wv >> 1, wc = wv & 1;
    const int lr = lane & 15, lk = lane >> 4;
    int row0, col0;
    xcd_tile<128, 128, 4>(row0, col0);
    const int sr = t >> 2;
    const int kc = t & 3;

    int aofs[4], bofs[4];
    #pragma unroll
    for (int fr = 0; fr < 4; ++fr) aofs[fr] = lofs(wr * 64 + fr * 16 + lr, lk);
    #pragma unroll
    for (int fc = 0; fc < 4; ++fc) bofs[fc] = lofs(wc * 64 + fc * 16 + lr, lk);
    const int so0 = lofs(sr, kc);
    const int so1 = lofs(64 + sr, kc);

    f32x4 acc[4][4];
    #pragma unroll
    for (int i = 0; i < 4; ++i)
        #pragma unroll
        for (int j = 0; j < 4; ++j) acc[i][j] = 0;

    for (int k0 = 0; k0 < K; k0 += 32) {
        u16x8 vah[2], val[2], vbh[2], vbl[2];
        #pragma unroll
        for (int p = 0; p < 2; ++p) {
            const size_t arow = (size_t)(row0 + p * 64 + sr) * K + k0 + kc * 8;
            vah[p] = *(const u16x8*)(Ahp + arow);
            val[p] = *(const u16x8*)(Alp + arow);
            const size_t brow = (size_t)(col0 + p * 64 + sr) * K + k0 + kc * 8;
            vbh[p] = *(const u16x8*)(Bh + brow);
            vbl[p] = *(const u16x8*)(Bl + brow);
        }

        __syncthreads();
        *(u16x8*)&Ah[so0]  = vah[0];  *(u16x8*)&Ah[so1]  = vah[1];
        *(u16x8*)&Al[so0]  = val[0];  *(u16x8*)&Al[so1]  = val[1];
        *(u16x8*)&Bsh[so0] = vbh[0];  *(u16x8*)&Bsh[so1] = vbh[1];
        *(u16x8*)&Bsl[so0] = vbl[0];  *(u16x8*)&Bsl[so1] = vbl[1];
        __syncthreads();

        bf16x8 bh[4], bl[4];
        #pragma unroll
        for (int fc = 0; fc < 4; ++fc) {
            bh[fc] = *(bf16x8*)&Bsh[bofs[fc]];
            bl[fc] = *(bf16x8*)&Bsl[bofs[fc]];
        }
        #pragma unroll
        for (int fr = 0; fr < 4; ++fr) {
            bf16x8 ah = *(bf16x8*)&Ah[aofs[fr]];
            bf16x8 al = *(bf16x8*)&Al[aofs[fr]];
            #pragma unroll
            for (int fc = 0; fc < 4; ++fc) {
                f32x4 a = acc[fr][fc];
                a = __builtin_amdgcn_mfma_f32_16x16x32_bf16(ah, bh[fc], a, 0, 0, 0);
                a = __builtin_amdgcn_mfma_f32_16x16x32_bf16(ah, bl[fc], a, 0, 0, 0);
                a = __builtin_amdgcn_mfma_f32_16x16x32_bf16(al, bh[fc], a, 0, 0, 0);
                acc[fr][fc] = a;
            }
        }
    }

    #pragma unroll
    for (int fr = 0; fr < 4; ++fr)
        #pragma unroll
        for (int fc = 0; fc < 4; ++fc) {
            int colg = col0 + wc * 64 + fc * 16 + lr;
            int rowb = row0 + wr * 64 + fr * 16 + lk * 4;
            float bv = bias[colg];
            #pragma unroll
            for (int i = 0; i < 4; ++i)
                out[(size_t)(rowb + i) * F1D + colg] = acc[fr][fc][i] + bv;
        }
}

// ---------------------------------------------------------------------------
// Fused: xa1 = gelu(pre1 @ Keff) -> bf16 pairs (for fc2e); o = xa1 @ w
// ---------------------------------------------------------------------------
template<int ROWS>
__global__ __launch_bounds__(256)
void kxo_kernel(const float* __restrict__ pre1, const float* __restrict__ Kb,
                const float* __restrict__ wb, const int* __restrict__ cs,
                u16* __restrict__ xa1h, u16* __restrict__ xa1l,
                float* __restrict__ o_out, int m)
{
    __shared__ float sKb[4][F1D];
    __shared__ float swb[4][SZD];
    __shared__ int   scs[SZD];
    __shared__ float spre[2][F1D];
    __shared__ float sxa[2][F1D];

    const int t = threadIdx.x;
    for (int i = t; i < 4 * F1D; i += 256) sKb[i >> 9][i & 511] = Kb[i];
    for (int i = t; i < 4 * SZD; i += 256) swb[i / SZD][i % SZD] = wb[i];
    if (t < SZD) scs[t] = cs[t];

    const int row_base = blockIdx.x * ROWS;
    const int rr = t >> 7;
    const int jc = t & 127;

    for (int ch = 0; ch < ROWS; ch += 2) {
        const int r0 = row_base + ch;
        __syncthreads();
        ((float4*)&spre[0][0])[t] = *(const float4*)(pre1 + (size_t)r0 * F1D + t * 4);
        __syncthreads();

        #pragma unroll
        for (int kk = 0; kk < 4; ++kk) {
            int j  = jc + (kk << 7);
            int jb = (j / m) * m;
            float s = 0.0f;
            for (int tt = 0; tt < 4; ++tt) {
                int i2 = jb + tt; if (i2 > F1D - 1) i2 = F1D - 1;
                s = fmaf(spre[rr][i2], sKb[tt][j], s);
            }
            float g = gelu_f(s);
            sxa[rr][j] = g;
            size_t oi = (size_t)(r0 + rr) * F1D + j;
            u16 gh = f2bf(g);
            xa1h[oi] = gh;
            xa1l[oi] = f2bf(g - bf2f(gh));
        }
        __syncthreads();

        for (int pos = t; pos < 2 * SZD; pos += 256) {
            int rr2 = pos / SZD, c = pos - rr2 * SZD;
            int s0 = scs[c];
            float s = 0.0f;
            #pragma unroll
            for (int tt = 0; tt < 4; ++tt) {
                int i2 = s0 + tt; if (i2 > F1D - 1) i2 = F1D - 1;
                s = fmaf(sxa[rr2][i2], swb[tt][c], s);
            }
            o_out[(size_t)(r0 + rr2) * SZD + c] = s;
        }
    }
}

// ---------------------------------------------------------------------------
// Fused: xa2 = gelu(pre2 @ Keff) [LDS only]; v = xa2 @ (W3*we) + b3
// ---------------------------------------------------------------------------
template<int ROWS>
__global__ __launch_bounds__(256)
void kv_kernel(const float* __restrict__ pre2, const float* __restrict__ Kb,
               const float* __restrict__ W3b, const float* __restrict__ b3,
               float* __restrict__ v_out, int m)
{
    __shared__ float sW3[15][F1D];
    __shared__ float sKb[4][F1D];
    __shared__ float sb3[F1D];
    __shared__ float spre[2][F1D];
    __shared__ float sxa[2][F1D];

    const int t = threadIdx.x;
    for (int i = t; i < 15 * F1D; i += 256) sW3[i >> 9][i & 511] = W3b[i];
    for (int i = t; i < 4 * F1D; i += 256)  sKb[i >> 9][i & 511] = Kb[i];
    for (int i = t; i < F1D; i += 256)      sb3[i] = b3[i];

    const int row_base = blockIdx.x * ROWS;
    const int rr = t >> 7;
    const int jc = t & 127;

    for (int ch = 0; ch < ROWS; ch += 2) {
        const int r0 = row_base + ch;
        __syncthreads();
        ((float4*)&spre[0][0])[t] = *(const float4*)(pre2 + (size_t)r0 * F1D + t * 4);
        __syncthreads();

        #pragma unroll
        for (int kk = 0; kk < 4; ++kk) {
            int j  = jc + (kk << 7);
            int jb = (j / m) * m;
            float s = 0.0f;
            for (int tt = 0; tt < 4; ++tt) {
                int i2 = jb + tt; if (i2 > F1D - 1) i2 = F1D - 1;
                s = fmaf(spre[rr][i2], sKb[tt][j], s);
            }
            sxa[rr][j] = gelu_f(s);
        }
        __syncthreads();

        #pragma unroll
        for (int kk = 0; kk < 4; ++kk) {
            int j = jc + (kk << 7);
            float s = sb3[j];
            #pragma unroll
            for (int d = 0; d < 15; ++d) {
                int i2 = j - 7 + d;
                if (i2 < 0) i2 = 0; if (i2 > F1D - 1) i2 = F1D - 1;
                s = fmaf(sxa[rr][i2], sW3[d][j], s);
            }
            v_out[(size_t)(r0 + rr) * F1D + j] = s;
        }
    }
}

extern "C" void kernel_launch(void* const* d_in, const int* in_sizes, int n_in,
                              void* d_out, int out_size, void* d_ws, size_t ws_size,
                              hipStream_t stream)
{
    const float* features = (const float*)d_in[0];
    const float* Wh1 = (const float*)d_in[1];
    const float* Mh1 = (const float*)d_in[2];
    const float* G1  = (const float*)d_in[3];
    const float* Wh2 = (const float*)d_in[4];
    const float* Mh2 = (const float*)d_in[5];
    const float* G2  = (const float*)d_in[6];
    const float* W1e = (const float*)d_in[7];
    const float* b1e = (const float*)d_in[8];
    const float* W2e = (const float*)d_in[9];
    const float* b2e = (const float*)d_in[10];
    const float* W3  = (const float*)d_in[11];
    const float* b3  = (const float*)d_in[12];
    const float* kn  = (const float*)d_in[13];
    const float* w   = (const float*)d_in[14];
    const float* we  = (const float*)d_in[15];

    int m = 1;
    { int s = in_sizes[13]; while (m * m < s) ++m; }   // m = sqrt(|kn|)

    // workspace (~134 MB peak)
    char* base = (char*)d_ws;
    size_t off = 0;
    auto alloc = [&](size_t bytes) { void* p = base + off; off += (bytes + 255) & ~255ull; return p; };
    u16*   W1h  = (u16*)alloc((size_t)F1D * FEATD * 2);
    u16*   W1l  = (u16*)alloc((size_t)F1D * FEATD * 2);
    u16*   G1h  = (u16*)alloc((size_t)F1D * FEATD * 2);
    u16*   G1l  = (u16*)alloc((size_t)F1D * FEATD * 2);
    u16*   W2h  = (u16*)alloc((size_t)F1D * F1D * 2);
    u16*   W2l  = (u16*)alloc((size_t)F1D * F1D * 2);
    u16*   G2h  = (u16*)alloc((size_t)F1D * F1D * 2);
    u16*   G2l  = (u16*)alloc((size_t)F1D * F1D * 2);
    u16*   W1eh = (u16*)alloc((size_t)F1D * 2 * F1D * 2);
    u16*   W1el = (u16*)alloc((size_t)F1D * 2 * F1D * 2);
    u16*   W2eh = (u16*)alloc((size_t)F1D * F1D * 2);
    u16*   W2el = (u16*)alloc((size_t)F1D * F1D * 2);
    float* Kb   = (float*)alloc(4 * F1D * 4);
    float* W3b  = (float*)alloc(15 * F1D * 4);
    float* wb   = (float*)alloc(4 * SZD * 4);
    int*   cs   = (int*)alloc(SZD * 4);
    u16*   h11h = (u16*)alloc((size_t)NROWS * F1D * 2);     // 16 MB  (-> pre1 region)
    u16*   h11l = (u16*)alloc((size_t)NROWS * F1D * 2);     // 16 MB
    u16*   l12h = (u16*)alloc((size_t)NROWS * F1D * 2);     // 16 MB  (-> pre2 region)
    u16*   l12l = (u16*)alloc((size_t)NROWS * F1D * 2);     // 16 MB
    u16*   hbh  = (u16*)alloc((size_t)NROWS * 2 * F1D * 2); // 32 MB
    u16*   hbl  = (u16*)alloc((size_t)NROWS * 2 * F1D * 2); // 32 MB
    float* pre1 = (float*)h11h;   // aliases L1 pair region (dead after L2)
    float* pre2 = (float*)l12h;

    float* o_out = (float*)d_out;
    float* v_out = (float*)d_out + (size_t)NROWS * SZD;
    u16* xa1h = (u16*)v_out;                    // parked in v-region
    u16* xa1l = xa1h + (size_t)NROWS * F1D;

    wprep_f16_kernel<<<(F1D * FEATD + 255) / 256, 256, 0, stream>>>(Wh1, Mh1, W1h, W1l, FEATD, F1D);
    wprep_f16_kernel<<<(F1D * FEATD + 255) / 256, 256, 0, stream>>>(G1, nullptr, G1h, G1l, FEATD, F1D);
    wprep_f16_kernel<<<(F1D * F1D + 255) / 256, 256, 0, stream>>>(Wh2, Mh2, W2h, W2l, F1D, F1D);
    wprep_f16_kernel<<<(F1D * F1D + 255) / 256, 256, 0, stream>>>(G2, nullptr, G2h, G2l, F1D, F1D);
    wprep2_kernel<<<(F1D * 2 * F1D + 255) / 256, 256, 0, stream>>>(W1e, W1eh, W1el, 2 * F1D, F1D);
    wprep2_kernel<<<(F1D * F1D + 255) / 256, 256, 0, stream>>>(W2e, W2eh, W2el, F1D, F1D);
    prep2_kernel<<<1, 512, 0, stream>>>(kn, we, W3, Kb, W3b, m);
    colrange_wband_kernel<<<1, 256, 0, stream>>>(w, cs, wb);

    dim3 gN(F1D / 64, NROWS / 128);    // (8, 128) = 1024 blocks
    dim3 gG(F1D / 128, NROWS / 128);   // (4, 128) = 512 blocks

    nalu_l1_kernel<FEATD><<<gN, 256, 0, stream>>>(
        features, W1h, W1l, G1h, G1l, h11h, h11l, l12h, l12l);
    nalu_l2_kernel<F1D><<<gN, 256, 0, stream>>>(
        h11h, h11l, l12h, l12l, W2h, W2l, G2h, G2l, hbh, hbl);

    gemm_mfma_kernel<2 * F1D><<<gG, 256, 0, stream>>>(hbh, hbl, W1eh, W1el, b1e, pre1);

    kxo_kernel<8><<<NROWS / 8, 256, 0, stream>>>(pre1, Kb, wb, cs, xa1h, xa1l, o_out, m);

    gemm_mfma_kernel<F1D><<<gG, 256, 0, stream>>>(xa1h, xa1l, W2eh, W2el, b2e, pre2);

    kv_kernel<8><<<NROWS / 8, 256, 0, stream>>>(pre2, Kb, W3b, b3, v_out, m);
}